// Round 1
// baseline (283.436 us; speedup 1.0000x reference)
//
#include <hip/hip_runtime.h>
#include <cstdint>

#pragma clang fp contract(off)

#define BB 64
#define PP 32768
#define OO 50
#define THRESH_F 0.5f
#define VAR0 0.1f
#define VAR1 0.2f
#define NEGPOS_I 3
#define SS 32            // k_loss splits per batch
#define T1 4             // priors per thread in k_match
#define NB0 2048         // pass-0 bins (bits 30:20)
#define NB12 1024        // pass-1/2 bins (10 bits each)

typedef unsigned long long u64;

// ---- K0: zero the atomically-accumulated region (hists + bpm) ----
__global__ void k_zero(float4* __restrict__ dst, int n4) {
    int i = blockIdx.x * blockDim.x + threadIdx.x;
    if (i < n4) dst[i] = make_float4(0.f, 0.f, 0.f, 0.f);
}

// wave64 max via DPP: row_shr 1/2/4/8 then row_bcast15 (rows 1,3) and
// row_bcast31 (rows 2,3). Valid for non-negative x (masked/invalid lanes
// contribute 0). Result in lane 63.
#define DPP_MAX(x, ctrl, rmask)                                              \
    x = fmaxf(x, __int_as_float(__builtin_amdgcn_update_dpp(                 \
            0, __float_as_int(x), (ctrl), (rmask), 0xf, true)));

// ---- K1: fused matcher. Each thread owns T1 consecutive priors; loops the 50
// truths computing each IoU once: row-best (per prior, regs) + column-best
// (per truth, DPP f32 wave max + ballot tie-break -> one atomicMax per wave).
// Packing (iou_bits<<32)|(PP-p): max == max IoU with smallest p on ties.
__global__ void __launch_bounds__(256, 8)
k_match(const float* __restrict__ priors, const float* __restrict__ targets,
        float* __restrict__ bto, int* __restrict__ bti, u64* __restrict__ bpm) {
    __shared__ float tr4[OO * 4];
    __shared__ float trA[OO];
    int b = blockIdx.y, tid = threadIdx.x;
    for (int i = tid; i < OO * 4; i += 256)
        tr4[i] = targets[(size_t)(b * OO + (i >> 2)) * 5 + (i & 3)];
    __syncthreads();
    if (tid < OO)
        trA[tid] = (tr4[tid*4+2] - tr4[tid*4]) * (tr4[tid*4+3] - tr4[tid*4+1]);
    __syncthreads();

    int p0 = blockIdx.x * (256 * T1) + tid * T1;
    float bx0[T1], by0[T1], bx1[T1], by1[T1], aB[T1];
#pragma unroll
    for (int j = 0; j < T1; ++j) {
        float4 pr = ((const float4*)priors)[p0 + j];
        bx0[j] = pr.x - pr.z * 0.5f; by0[j] = pr.y - pr.w * 0.5f;
        bx1[j] = pr.x + pr.z * 0.5f; by1[j] = pr.y + pr.w * 0.5f;
        aB[j] = (bx1[j] - bx0[j]) * (by1[j] - by0[j]);
    }
    float rbv[T1]; int rbi[T1];
#pragma unroll
    for (int j = 0; j < T1; ++j) { rbv[j] = -1.0f; rbi[j] = 0; }

    for (int t = 0; t < OO; ++t) {
        float t0 = tr4[t*4], t1v = tr4[t*4+1], t2 = tr4[t*4+2], t3 = tr4[t*4+3];
        float aA = trA[t];
        float cbv = -1.0f; int cbp = 0;
#pragma unroll
        for (int j = 0; j < T1; ++j) {
            float ltx = fmaxf(t0, bx0[j]), lty = fmaxf(t1v, by0[j]);
            float rbx = fminf(t2, bx1[j]), rby = fminf(t3, by1[j]);
            float wx = fmaxf(rbx - ltx, 0.f), wy = fmaxf(rby - lty, 0.f);
            float inter = wx * wy;
            float v = inter / (aA + aB[j] - inter);
            if (v > rbv[j]) { rbv[j] = v; rbi[j] = t; }   // row: first-max (strict >)
            if (v > cbv) { cbv = v; cbp = p0 + j; }       // col: smallest p on ties
        }
        // wave-level column-best: f32 DPP max (cbv >= 0 always), then pick
        // the lowest lane holding the max (lanes are ordered by prior index).
        float x = cbv;
        DPP_MAX(x, 0x111, 0xf);   // row_shr:1
        DPP_MAX(x, 0x112, 0xf);   // row_shr:2
        DPP_MAX(x, 0x114, 0xf);   // row_shr:4
        DPP_MAX(x, 0x118, 0xf);   // row_shr:8
        DPP_MAX(x, 0x142, 0xa);   // row_bcast:15 -> rows 1,3
        DPP_MAX(x, 0x143, 0xc);   // row_bcast:31 -> rows 2,3
        float mv = __int_as_float(__builtin_amdgcn_readlane(__float_as_int(x), 63));
        unsigned long long msk = __ballot(cbv == mv);
        int lane = (int)__ffsll((long long)msk) - 1;
        int pwin = __builtin_amdgcn_readlane(cbp, lane);
        if ((tid & 63) == 0) {
            u64 pk = ((u64)__float_as_uint(mv) << 32) | (unsigned)(PP - pwin);
            atomicMax(&bpm[b * OO + t], pk);
        }
    }
    size_t bp = (size_t)b * PP + p0;
    ((float4*)bto)[bp >> 2] = make_float4(rbv[0], rbv[1], rbv[2], rbv[3]);
    ((int4*)bti)[bp >> 2]   = make_int4(rbi[0], rbi[1], rbi[2], rbi[3]);
}

// ---- K2: forced match — sequential per batch, last write wins ----
__global__ void k_force(const u64* __restrict__ bpm,
                        float* __restrict__ bto, int* __restrict__ bti) {
    __shared__ int pidx[OO];
    int b = blockIdx.x, tid = threadIdx.x;
    if (tid < OO) pidx[tid] = PP - (int)(unsigned)(bpm[b * OO + tid] & 0xFFFFFFFFull);
    __syncthreads();
    if (tid == 0) {
        for (int j = 0; j < OO; ++j) {
            int p = pidx[j];
            bto[(size_t)b * PP + p] = 2.0f;
            bti[(size_t)b * PP + p] = j;
        }
    }
}

// ---- K3: conf/encode/smooth-L1/lc; writes lcm + per-block partials ----
__global__ void __launch_bounds__(256)
k_loss(const float* __restrict__ arm_loc, const float* __restrict__ arm_conf,
       const float* __restrict__ priors, const float* __restrict__ targets,
       const float* __restrict__ bto, const int* __restrict__ bti,
       float* __restrict__ lcm, float* __restrict__ pll,
       float* __restrict__ pplc, int* __restrict__ pnp) {
    int b = blockIdx.y, s = blockIdx.x, tid = threadIdx.x;
    int p = s * 1024 + tid * 4;
    size_t bp = (size_t)b * PP + p;

    float4 ov4 = ((const float4*)bto)[bp >> 2];
    int4   ti4 = ((const int4*)bti)[bp >> 2];
    float4 ca  = ((const float4*)arm_conf)[bp >> 1];
    float4 cb  = ((const float4*)arm_conf)[(bp >> 1) + 1];
    float ovs[4] = {ov4.x, ov4.y, ov4.z, ov4.w};
    int   tis[4] = {ti4.x, ti4.y, ti4.z, ti4.w};
    float cs[8]  = {ca.x, ca.y, ca.z, ca.w, cb.x, cb.y, cb.z, cb.w};

    float ll = 0.0f, plc = 0.0f; int np = 0;
    float outv[4];
    for (int c = 0; c < 4; ++c) {
        int ti = tis[c];
        const float* tb = &targets[(size_t)(b * OO + ti) * 5];
        int label = (tb[4] >= 0.0f) ? 1 : 0;
        int conf = (ovs[c] < THRESH_F) ? 0 : label;
        float c0 = cs[c * 2], c1 = cs[c * 2 + 1];
        float m = fmaxf(c0, c1);
        float lse = logf(expf(c0 - m) + expf(c1 - m)) + m;
        float picked = (conf == 1) ? c1 : c0;
        float lc = lse - picked;
        bool pos = conf > 0;
        outv[c] = pos ? 0.0f : lc;
        if (pos) {
            np++; plc += lc;
            float4 pr = ((const float4*)priors)[p + c];
            float gx = ((tb[0] + tb[2]) * 0.5f - pr.x) / (VAR0 * pr.z);
            float gy = ((tb[1] + tb[3]) * 0.5f - pr.y) / (VAR0 * pr.w);
            float gw = logf((tb[2] - tb[0]) / pr.z) / VAR1;
            float gh = logf((tb[3] - tb[1]) / pr.w) / VAR1;
            float g[4] = {gx, gy, gw, gh};
            float4 ld = ((const float4*)arm_loc)[bp + c];
            float lds_[4] = {ld.x, ld.y, ld.z, ld.w};
            for (int q = 0; q < 4; ++q) {
                float d = lds_[q] - g[q];
                float ad = fabsf(d);
                ll += (ad < 1.0f) ? 0.5f * d * d : ad - 0.5f;
            }
        }
    }
    ((float4*)lcm)[bp >> 2] = make_float4(outv[0], outv[1], outv[2], outv[3]);

    __shared__ float s1[256], s2[256]; __shared__ int s3[256];
    s1[tid] = ll; s2[tid] = plc; s3[tid] = np;
    __syncthreads();
    for (int st = 128; st > 0; st >>= 1) {
        if (tid < st) { s1[tid] += s1[tid+st]; s2[tid] += s2[tid+st]; s3[tid] += s3[tid+st]; }
        __syncthreads();
    }
    if (tid == 0) {
        pll[s * BB + b] = s1[0];
        pplc[s * BB + b] = s2[0];
        pnp[s * BB + b] = s3[0];
    }
}

// ---- K4 hist: multi-block per-batch histogram (count + value sum) ----
template <int PASS>
__global__ void __launch_bounds__(256)
k_hist(const float* __restrict__ lcm, const unsigned* __restrict__ spre,
       int* __restrict__ Hc, float* __restrict__ Hs) {
    const int nbins = (PASS == 0) ? NB0 : NB12;
    __shared__ int hc[NB0]; __shared__ float hs[NB0];
    int b = blockIdx.y, tid = threadIdx.x;
    for (int i = tid; i < nbins; i += 256) { hc[i] = 0; hs[i] = 0.f; }
    __syncthreads();
    unsigned pref = (PASS == 0) ? 0u : spre[b];
    const float4* v4 = (const float4*)(lcm + (size_t)b * PP);
    int base = blockIdx.x * 1024;
    for (int i = 0; i < 4; ++i) {
        float4 x = v4[base + i * 256 + tid];
        float xs[4] = {x.x, x.y, x.z, x.w};
        for (int c = 0; c < 4; ++c) {
            unsigned u = __float_as_uint(xs[c]);
            bool ok; unsigned bin;
            if (PASS == 0)      { ok = true;               bin = u >> 20; }
            else if (PASS == 1) { ok = (u >> 20) == pref;  bin = (u >> 10) & 1023u; }
            else                { ok = (u >> 10) == pref;  bin = u & 1023u; }
            if (ok) { atomicAdd(&hc[bin], 1); atomicAdd(&hs[bin], xs[c]); }
        }
    }
    __syncthreads();
    for (int i = tid; i < nbins; i += 256) {
        int cv = hc[i];
        if (cv) {
            atomicAdd(&Hc[b * nbins + i], cv);
            atomicAdd(&Hs[b * nbins + i], hs[i]);
        }
    }
}

// ---- K4 scan: parallel suffix-scan of a batch histogram; selects the bin
// containing the k-th largest, accumulates sum/count of all higher bins. ----
__global__ void __launch_bounds__(256)
k_scan(const int* __restrict__ Hc, const float* __restrict__ Hs, int nbins,
       int pass, const int* __restrict__ pnp, unsigned* __restrict__ spre,
       int* __restrict__ srem, float* __restrict__ ssum,
       unsigned* __restrict__ stb) {
    int b = blockIdx.x, tid = threadIdx.x;
    int CH = nbins >> 8;
    const int* hc = Hc + b * nbins;
    const float* hs = Hs + b * nbins;
    __shared__ int sc[256]; __shared__ float sf[256];
    __shared__ int s_chunk; __shared__ int s_r; __shared__ float s_S;

    int c = 0; float f = 0.f;
    int base = tid * CH;
    for (int i = 0; i < CH; ++i) { c += hc[base + i]; f += hs[base + i]; }
    sc[tid] = c; sf[tid] = f;
    __syncthreads();
    // inclusive suffix sums via Hillis-Steele
    for (int off = 1; off < 256; off <<= 1) {
        int cv = (tid + off < 256) ? sc[tid + off] : 0;
        float fv = (tid + off < 256) ? sf[tid + off] : 0.f;
        __syncthreads();
        sc[tid] += cv; sf[tid] += fv;
        __syncthreads();
    }
    if (tid == 0) {
        int r; float S;
        if (pass == 0) {
            int np = 0;
            for (int i = 0; i < SS; ++i) np += pnp[i * BB + b];
            int k = NEGPOS_I * np; if (k > PP - 1) k = PP - 1;
            r = k; S = 0.f;
        } else { r = srem[b]; S = ssum[b]; }
        s_r = r; s_S = S;
    }
    __syncthreads();
    int r = s_r;
    int nxt = (tid == 255) ? 0 : sc[tid + 1];
    if (sc[tid] >= r && nxt < r) s_chunk = tid;
    __syncthreads();
    if (tid == 0) {
        int ch = s_chunk;
        int r2 = r - ((ch == 255) ? 0 : sc[ch + 1]);
        float S2 = s_S + ((ch == 255) ? 0.f : sf[ch + 1]);
        int binSel = ch * CH;
        for (int i = CH - 1; i >= 0; --i) {
            int bin = ch * CH + i;
            int cb = hc[bin];
            if (r2 <= cb) { binSel = bin; break; }
            r2 -= cb; S2 += hs[bin];
        }
        unsigned pref = (pass == 0) ? (unsigned)binSel
                                    : ((spre[b] << 10) | (unsigned)binSel);
        spre[b] = pref; srem[b] = r2; ssum[b] = S2;
        if (pass == 2) stb[b] = pref;
    }
}

// ---- K5: final reduction across batches -> (loss_l/N, loss_c/N) ----
__global__ void k_final(const float* __restrict__ pll, const float* __restrict__ pplc,
                        const int* __restrict__ pnp, const float* __restrict__ ssum,
                        const int* __restrict__ srem, const unsigned* __restrict__ stb,
                        float* __restrict__ out) {
    int b = threadIdx.x;          // 64 threads = one wave, one batch each
    float ll = 0.f, plc = 0.f; int np = 0;
    for (int s = 0; s < SS; ++s) {
        ll += pll[s * BB + b];
        plc += pplc[s * BB + b];
        np += pnp[s * BB + b];
    }
    float tval = __uint_as_float(stb[b]);
    float cc = plc + ssum[b] + (float)srem[b] * tval;
    for (int s = 32; s > 0; s >>= 1) {
        ll += __shfl_down(ll, s);
        cc += __shfl_down(cc, s);
        np += __shfl_down(np, s);
    }
    if (b == 0) {
        float N = (float)np;
        out[0] = ll / N;
        out[1] = cc / N;
    }
}

extern "C" void kernel_launch(void* const* d_in, const int* in_sizes, int n_in,
                              void* d_out, int out_size, void* d_ws, size_t ws_size,
                              hipStream_t stream) {
    const float* arm_loc  = (const float*)d_in[0];
    const float* arm_conf = (const float*)d_in[1];
    const float* priors   = (const float*)d_in[4];
    const float* targets  = (const float*)d_in[5];
    float* out = (float*)d_out;

    char* w = (char*)d_ws;
    float* bto = (float*)w;  w += sizeof(float) * (size_t)BB * PP;    // 8 MB
    int*   bti = (int*)w;    w += sizeof(int)   * (size_t)BB * PP;    // 8 MB
    float* lcm = (float*)w;  w += sizeof(float) * (size_t)BB * PP;    // 8 MB
    // ---- zeroed region (atomically accumulated) ----
    char* zbase = w;
    int*   Hc0 = (int*)w;    w += sizeof(int)   * BB * NB0;
    float* Hs0 = (float*)w;  w += sizeof(float) * BB * NB0;
    int*   Hc1 = (int*)w;    w += sizeof(int)   * BB * NB12;
    float* Hs1 = (float*)w;  w += sizeof(float) * BB * NB12;
    int*   Hc2 = (int*)w;    w += sizeof(int)   * BB * NB12;
    float* Hs2 = (float*)w;  w += sizeof(float) * BB * NB12;
    u64*   bpm = (u64*)w;    w += sizeof(u64)   * BB * OO;
    size_t zbytes = (size_t)(w - zbase);
    // ---- plain written-before-read region ----
    float* pll  = (float*)w; w += sizeof(float) * BB * SS;
    float* pplc = (float*)w; w += sizeof(float) * BB * SS;
    int*   pnp  = (int*)w;   w += sizeof(int)   * BB * SS;
    unsigned* spre = (unsigned*)w; w += sizeof(unsigned) * BB;
    int*      srem = (int*)w;      w += sizeof(int) * BB;
    float*    ssum = (float*)w;    w += sizeof(float) * BB;
    unsigned* stb  = (unsigned*)w; w += sizeof(unsigned) * BB;

    int n4 = (int)(zbytes / 16);
    k_zero<<<(n4 + 255) / 256, 256, 0, stream>>>((float4*)zbase, n4);
    k_match<<<dim3(PP / (256 * T1), BB), 256, 0, stream>>>(priors, targets, bto, bti, bpm);
    k_force<<<BB, 64, 0, stream>>>(bpm, bto, bti);
    k_loss<<<dim3(SS, BB), 256, 0, stream>>>(arm_loc, arm_conf, priors, targets,
                                             bto, bti, lcm, pll, pplc, pnp);
    k_hist<0><<<dim3(8, BB), 256, 0, stream>>>(lcm, spre, Hc0, Hs0);
    k_scan<<<BB, 256, 0, stream>>>(Hc0, Hs0, NB0, 0, pnp, spre, srem, ssum, stb);
    k_hist<1><<<dim3(8, BB), 256, 0, stream>>>(lcm, spre, Hc1, Hs1);
    k_scan<<<BB, 256, 0, stream>>>(Hc1, Hs1, NB12, 1, pnp, spre, srem, ssum, stb);
    k_hist<2><<<dim3(8, BB), 256, 0, stream>>>(lcm, spre, Hc2, Hs2);
    k_scan<<<BB, 256, 0, stream>>>(Hc2, Hs2, NB12, 2, pnp, spre, srem, ssum, stb);
    k_final<<<1, 64, 0, stream>>>(pll, pplc, pnp, ssum, srem, stb, out);
}

// Round 2
// 275.774 us; speedup vs baseline: 1.0278x; 1.0278x over previous
//
#include <hip/hip_runtime.h>
#include <cstdint>

#pragma clang fp contract(off)

#define BB 64
#define PP 32768
#define OO 50
#define THRESH_F 0.5f
#define VAR0 0.1f
#define VAR1 0.2f
#define NEGPOS_I 3
#define SS 32            // k_loss splits per batch
#define T1 4             // priors per thread in k_match
#define NB0 2048         // pass-0 bins (bits 30:20)
#define NB12 1024        // pass-1/2 bins (10 bits each)

typedef unsigned long long u64;

// ---- K0: zero the atomically-accumulated region (hists + bpm), and
// (blockIdx.y==1) prep the packed truth table: trT[b][t] = {x0,y0,x1,y1},
// trAr[b][t] = area. One extra guard slot at the end for prefetch. ----
__global__ void k_zero(float4* __restrict__ dst, int n4,
                       const float* __restrict__ targets,
                       float4* __restrict__ trT, float* __restrict__ trAr) {
    if (blockIdx.y == 0) {
        int i = blockIdx.x * blockDim.x + threadIdx.x;
        if (i < n4) dst[i] = make_float4(0.f, 0.f, 0.f, 0.f);
    } else {
        int b = blockIdx.x, t = threadIdx.x;
        if (b < BB && t < OO) {
            const float* tb = &targets[(size_t)(b * OO + t) * 5];
            float x0 = tb[0], y0 = tb[1], x1 = tb[2], y1 = tb[3];
            trT[b * OO + t] = make_float4(x0, y0, x1, y1);
            trAr[b * OO + t] = (x1 - x0) * (y1 - y0);
        }
        if (b == 0 && t == 0) {   // init guard slot (value unused)
            trT[BB * OO] = make_float4(0.f, 0.f, 0.f, 0.f);
            trAr[BB * OO] = 1.0f;
        }
    }
}

// wave64 max via DPP with identity old (fusable to v_max_f32_dpp):
// row_shr 1/2/4/8 then row_bcast15 (rows 1,3) and row_bcast31 (rows 2,3).
// Result in lane 63.
#define DPP_MAX(x, ctrl, rmask)                                              \
    {                                                                        \
        int _o = __float_as_int(x);                                          \
        x = fmaxf(x, __int_as_float(__builtin_amdgcn_update_dpp(             \
                _o, _o, (ctrl), (rmask), 0xf, false)));                      \
    }

// ---- K1: fused matcher. Each thread owns T1 consecutive priors; loops the 50
// truths computing each IoU once: row-best (per prior, regs) + column-best
// (per truth, DPP f32 wave max + ballot tie-break -> one atomicMax per wave).
// Truth data comes from the packed table via wave-uniform loads (SMEM path):
// no LDS, no barriers, no per-iteration VALU address math.
__global__ void __launch_bounds__(256, 8)
k_match(const float* __restrict__ priors, const float4* __restrict__ trT,
        const float* __restrict__ trAr,
        float* __restrict__ bto, int* __restrict__ bti, u64* __restrict__ bpm) {
    int b = blockIdx.y, tid = threadIdx.x;

    int p0 = blockIdx.x * (256 * T1) + tid * T1;
    float bx0[T1], by0[T1], bx1[T1], by1[T1], aB[T1];
#pragma unroll
    for (int j = 0; j < T1; ++j) {
        float4 pr = ((const float4*)priors)[p0 + j];
        bx0[j] = pr.x - pr.z * 0.5f; by0[j] = pr.y - pr.w * 0.5f;
        bx1[j] = pr.x + pr.z * 0.5f; by1[j] = pr.y + pr.w * 0.5f;
        aB[j] = (bx1[j] - bx0[j]) * (by1[j] - by0[j]);
    }
    float rbv[T1]; int rbi[T1];
#pragma unroll
    for (int j = 0; j < T1; ++j) { rbv[j] = -1.0f; rbi[j] = 0; }

    int tb0 = b * OO;
    float4 tt = trT[tb0];
    float aA = trAr[tb0];

    for (int t = 0; t < OO; ++t) {
        // prefetch next truth (guard slot makes t=OO-1 safe)
        float4 ttn = trT[tb0 + t + 1];
        float aAn = trAr[tb0 + t + 1];

        float t0 = tt.x, t1v = tt.y, t2 = tt.z, t3 = tt.w;
        float cbv = -1.0f; int cbp = 0;
#pragma unroll
        for (int j = 0; j < T1; ++j) {
            float ltx = fmaxf(t0, bx0[j]), lty = fmaxf(t1v, by0[j]);
            float rbx = fminf(t2, bx1[j]), rby = fminf(t3, by1[j]);
            float wx = fmaxf(rbx - ltx, 0.f), wy = fmaxf(rby - lty, 0.f);
            float inter = wx * wy;
            float v = inter / (aA + aB[j] - inter);
            if (v > rbv[j]) { rbv[j] = v; rbi[j] = t; }   // row: first-max (strict >)
            if (v > cbv) { cbv = v; cbp = p0 + j; }       // col: smallest p on ties
        }
        // wave-level column-best: f32 DPP max (cbv >= 0 always), then pick
        // the lowest lane holding the max (lanes are ordered by prior index).
        float x = cbv;
        DPP_MAX(x, 0x111, 0xf);   // row_shr:1
        DPP_MAX(x, 0x112, 0xf);   // row_shr:2
        DPP_MAX(x, 0x114, 0xf);   // row_shr:4
        DPP_MAX(x, 0x118, 0xf);   // row_shr:8
        DPP_MAX(x, 0x142, 0xa);   // row_bcast:15 -> rows 1,3
        DPP_MAX(x, 0x143, 0xc);   // row_bcast:31 -> rows 2,3
        float mv = __int_as_float(__builtin_amdgcn_readlane(__float_as_int(x), 63));
        unsigned long long msk = __ballot(cbv == mv);
        int lane = (int)__ffsll((long long)msk) - 1;
        int pwin = __builtin_amdgcn_readlane(cbp, lane);
        if ((tid & 63) == 0) {
            u64 pk = ((u64)__float_as_uint(mv) << 32) | (unsigned)(PP - pwin);
            atomicMax(&bpm[b * OO + t], pk);
        }
        tt = ttn; aA = aAn;
    }
    size_t bp = (size_t)b * PP + p0;
    ((float4*)bto)[bp >> 2] = make_float4(rbv[0], rbv[1], rbv[2], rbv[3]);
    ((int4*)bti)[bp >> 2]   = make_int4(rbi[0], rbi[1], rbi[2], rbi[3]);
}

// ---- K2: forced match — parallel, last-write-wins via dedup: lane j writes
// only if no later truth j' maps to the same prior. ----
__global__ void k_force(const u64* __restrict__ bpm,
                        float* __restrict__ bto, int* __restrict__ bti) {
    int b = blockIdx.x, j = threadIdx.x;   // 64 threads, one wave
    int p = -1;
    if (j < OO) p = PP - (int)(unsigned)(bpm[b * OO + j] & 0xFFFFFFFFull);
    bool w = (j < OO);
    for (int jj = 1; jj < OO; ++jj) {
        int pj = __shfl(p, jj, 64);
        if (jj > j && pj == p) w = false;
    }
    if (w) {
        bto[(size_t)b * PP + p] = 2.0f;
        bti[(size_t)b * PP + p] = j;
    }
}

// ---- K3: conf/encode/smooth-L1/lc; writes lcm + per-block partials.
// Pass-0 histogram (bits 30:20, 2048 bins) fused in: LDS-private, merged
// into the global Hc0/Hs0 via atomics. ----
__global__ void __launch_bounds__(256)
k_loss(const float* __restrict__ arm_loc, const float* __restrict__ arm_conf,
       const float* __restrict__ priors, const float* __restrict__ targets,
       const float* __restrict__ bto, const int* __restrict__ bti,
       float* __restrict__ lcm, float* __restrict__ pll,
       float* __restrict__ pplc, int* __restrict__ pnp,
       int* __restrict__ Hc0, float* __restrict__ Hs0) {
    __shared__ int hc[NB0]; __shared__ float hs[NB0];
    int b = blockIdx.y, s = blockIdx.x, tid = threadIdx.x;
    for (int i = tid; i < NB0; i += 256) { hc[i] = 0; hs[i] = 0.f; }
    __syncthreads();

    int p = s * 1024 + tid * 4;
    size_t bp = (size_t)b * PP + p;

    float4 ov4 = ((const float4*)bto)[bp >> 2];
    int4   ti4 = ((const int4*)bti)[bp >> 2];
    float4 ca  = ((const float4*)arm_conf)[bp >> 1];
    float4 cb  = ((const float4*)arm_conf)[(bp >> 1) + 1];
    float ovs[4] = {ov4.x, ov4.y, ov4.z, ov4.w};
    int   tis[4] = {ti4.x, ti4.y, ti4.z, ti4.w};
    float cs[8]  = {ca.x, ca.y, ca.z, ca.w, cb.x, cb.y, cb.z, cb.w};

    float ll = 0.0f, plc = 0.0f; int np = 0;
    float outv[4];
    for (int c = 0; c < 4; ++c) {
        int ti = tis[c];
        const float* tb = &targets[(size_t)(b * OO + ti) * 5];
        int label = (tb[4] >= 0.0f) ? 1 : 0;
        int conf = (ovs[c] < THRESH_F) ? 0 : label;
        float c0 = cs[c * 2], c1 = cs[c * 2 + 1];
        float m = fmaxf(c0, c1);
        float lse = logf(expf(c0 - m) + expf(c1 - m)) + m;
        float picked = (conf == 1) ? c1 : c0;
        float lc = lse - picked;
        bool pos = conf > 0;
        outv[c] = pos ? 0.0f : lc;
        if (pos) {
            np++; plc += lc;
            float4 pr = ((const float4*)priors)[p + c];
            float gx = ((tb[0] + tb[2]) * 0.5f - pr.x) / (VAR0 * pr.z);
            float gy = ((tb[1] + tb[3]) * 0.5f - pr.y) / (VAR0 * pr.w);
            float gw = logf((tb[2] - tb[0]) / pr.z) / VAR1;
            float gh = logf((tb[3] - tb[1]) / pr.w) / VAR1;
            float g[4] = {gx, gy, gw, gh};
            float4 ld = ((const float4*)arm_loc)[bp + c];
            float lds_[4] = {ld.x, ld.y, ld.z, ld.w};
            for (int q = 0; q < 4; ++q) {
                float d = lds_[q] - g[q];
                float ad = fabsf(d);
                ll += (ad < 1.0f) ? 0.5f * d * d : ad - 0.5f;
            }
        }
        unsigned u = __float_as_uint(outv[c]);
        atomicAdd(&hc[u >> 20], 1);
        atomicAdd(&hs[u >> 20], outv[c]);
    }
    ((float4*)lcm)[bp >> 2] = make_float4(outv[0], outv[1], outv[2], outv[3]);

    __shared__ float s1[256], s2[256]; __shared__ int s3[256];
    s1[tid] = ll; s2[tid] = plc; s3[tid] = np;
    __syncthreads();
    for (int st = 128; st > 0; st >>= 1) {
        if (tid < st) { s1[tid] += s1[tid+st]; s2[tid] += s2[tid+st]; s3[tid] += s3[tid+st]; }
        __syncthreads();
    }
    if (tid == 0) {
        pll[s * BB + b] = s1[0];
        pplc[s * BB + b] = s2[0];
        pnp[s * BB + b] = s3[0];
    }
    // merge pass-0 histogram (all LDS atomics complete before last barrier)
    for (int i = tid; i < NB0; i += 256) {
        int cv = hc[i];
        if (cv) {
            atomicAdd(&Hc0[b * NB0 + i], cv);
            atomicAdd(&Hs0[b * NB0 + i], hs[i]);
        }
    }
}

// ---- K4 hist (passes 1,2): 32 blocks per batch, 1024 elements each ----
template <int PASS>
__global__ void __launch_bounds__(256)
k_hist(const float* __restrict__ lcm, const unsigned* __restrict__ spre,
       int* __restrict__ Hc, float* __restrict__ Hs) {
    __shared__ int hc[NB12]; __shared__ float hs[NB12];
    int b = blockIdx.y, tid = threadIdx.x;
    for (int i = tid; i < NB12; i += 256) { hc[i] = 0; hs[i] = 0.f; }
    __syncthreads();
    unsigned pref = spre[b];
    float4 x = ((const float4*)(lcm + (size_t)b * PP))[blockIdx.x * 256 + tid];
    float xs[4] = {x.x, x.y, x.z, x.w};
    for (int c = 0; c < 4; ++c) {
        unsigned u = __float_as_uint(xs[c]);
        bool ok; unsigned bin;
        if (PASS == 1) { ok = (u >> 20) == pref;  bin = (u >> 10) & 1023u; }
        else           { ok = (u >> 10) == pref;  bin = u & 1023u; }
        if (ok) { atomicAdd(&hc[bin], 1); atomicAdd(&hs[bin], xs[c]); }
    }
    __syncthreads();
    for (int i = tid; i < NB12; i += 256) {
        int cv = hc[i];
        if (cv) {
            atomicAdd(&Hc[b * NB12 + i], cv);
            atomicAdd(&Hs[b * NB12 + i], hs[i]);
        }
    }
}

// ---- K4 scan: parallel suffix-scan of a batch histogram; selects the bin
// containing the k-th largest, accumulates sum/count of all higher bins. ----
__global__ void __launch_bounds__(256)
k_scan(const int* __restrict__ Hc, const float* __restrict__ Hs, int nbins,
       int pass, const int* __restrict__ pnp, unsigned* __restrict__ spre,
       int* __restrict__ srem, float* __restrict__ ssum,
       unsigned* __restrict__ stb) {
    int b = blockIdx.x, tid = threadIdx.x;
    int CH = nbins >> 8;
    const int* hc = Hc + b * nbins;
    const float* hs = Hs + b * nbins;
    __shared__ int sc[256]; __shared__ float sf[256];
    __shared__ int s_chunk; __shared__ int s_r; __shared__ float s_S;

    int c = 0; float f = 0.f;
    int base = tid * CH;
    for (int i = 0; i < CH; ++i) { c += hc[base + i]; f += hs[base + i]; }
    sc[tid] = c; sf[tid] = f;
    __syncthreads();
    // inclusive suffix sums via Hillis-Steele
    for (int off = 1; off < 256; off <<= 1) {
        int cv = (tid + off < 256) ? sc[tid + off] : 0;
        float fv = (tid + off < 256) ? sf[tid + off] : 0.f;
        __syncthreads();
        sc[tid] += cv; sf[tid] += fv;
        __syncthreads();
    }
    if (tid == 0) {
        int r; float S;
        if (pass == 0) {
            int np = 0;
            for (int i = 0; i < SS; ++i) np += pnp[i * BB + b];
            int k = NEGPOS_I * np; if (k > PP - 1) k = PP - 1;
            r = k; S = 0.f;
        } else { r = srem[b]; S = ssum[b]; }
        s_r = r; s_S = S;
    }
    __syncthreads();
    int r = s_r;
    int nxt = (tid == 255) ? 0 : sc[tid + 1];
    if (sc[tid] >= r && nxt < r) s_chunk = tid;
    __syncthreads();
    if (tid == 0) {
        int ch = s_chunk;
        int r2 = r - ((ch == 255) ? 0 : sc[ch + 1]);
        float S2 = s_S + ((ch == 255) ? 0.f : sf[ch + 1]);
        int binSel = ch * CH;
        for (int i = CH - 1; i >= 0; --i) {
            int bin = ch * CH + i;
            int cb = hc[bin];
            if (r2 <= cb) { binSel = bin; break; }
            r2 -= cb; S2 += hs[bin];
        }
        unsigned pref = (pass == 0) ? (unsigned)binSel
                                    : ((spre[b] << 10) | (unsigned)binSel);
        spre[b] = pref; srem[b] = r2; ssum[b] = S2;
        if (pass == 2) stb[b] = pref;
    }
}

// ---- K5: final reduction across batches -> (loss_l/N, loss_c/N) ----
__global__ void k_final(const float* __restrict__ pll, const float* __restrict__ pplc,
                        const int* __restrict__ pnp, const float* __restrict__ ssum,
                        const int* __restrict__ srem, const unsigned* __restrict__ stb,
                        float* __restrict__ out) {
    int b = threadIdx.x;          // 64 threads = one wave, one batch each
    float ll = 0.f, plc = 0.f; int np = 0;
    for (int s = 0; s < SS; ++s) {
        ll += pll[s * BB + b];
        plc += pplc[s * BB + b];
        np += pnp[s * BB + b];
    }
    float tval = __uint_as_float(stb[b]);
    float cc = plc + ssum[b] + (float)srem[b] * tval;
    for (int s = 32; s > 0; s >>= 1) {
        ll += __shfl_down(ll, s);
        cc += __shfl_down(cc, s);
        np += __shfl_down(np, s);
    }
    if (b == 0) {
        float N = (float)np;
        out[0] = ll / N;
        out[1] = cc / N;
    }
}

extern "C" void kernel_launch(void* const* d_in, const int* in_sizes, int n_in,
                              void* d_out, int out_size, void* d_ws, size_t ws_size,
                              hipStream_t stream) {
    const float* arm_loc  = (const float*)d_in[0];
    const float* arm_conf = (const float*)d_in[1];
    const float* priors   = (const float*)d_in[4];
    const float* targets  = (const float*)d_in[5];
    float* out = (float*)d_out;

    char* w = (char*)d_ws;
    float* bto = (float*)w;  w += sizeof(float) * (size_t)BB * PP;    // 8 MB
    int*   bti = (int*)w;    w += sizeof(int)   * (size_t)BB * PP;    // 8 MB
    float* lcm = (float*)w;  w += sizeof(float) * (size_t)BB * PP;    // 8 MB
    // ---- zeroed region (atomically accumulated) ----
    char* zbase = w;
    int*   Hc0 = (int*)w;    w += sizeof(int)   * BB * NB0;
    float* Hs0 = (float*)w;  w += sizeof(float) * BB * NB0;
    int*   Hc1 = (int*)w;    w += sizeof(int)   * BB * NB12;
    float* Hs1 = (float*)w;  w += sizeof(float) * BB * NB12;
    int*   Hc2 = (int*)w;    w += sizeof(int)   * BB * NB12;
    float* Hs2 = (float*)w;  w += sizeof(float) * BB * NB12;
    u64*   bpm = (u64*)w;    w += sizeof(u64)   * BB * OO;
    size_t zbytes = (size_t)(w - zbase);
    // ---- plain written-before-read region ----
    float* pll  = (float*)w; w += sizeof(float) * BB * SS;
    float* pplc = (float*)w; w += sizeof(float) * BB * SS;
    int*   pnp  = (int*)w;   w += sizeof(int)   * BB * SS;
    unsigned* spre = (unsigned*)w; w += sizeof(unsigned) * BB;
    int*      srem = (int*)w;      w += sizeof(int) * BB;
    float*    ssum = (float*)w;    w += sizeof(float) * BB;
    unsigned* stb  = (unsigned*)w; w += sizeof(unsigned) * BB;
    float4* trT = (float4*)w;      w += sizeof(float4) * (BB * OO + 1);
    float*  trAr = (float*)w;      w += sizeof(float)  * (BB * OO + 1);

    int n4 = (int)(zbytes / 16);
    int nzb = (n4 + 255) / 256; if (nzb < BB) nzb = BB;
    k_zero<<<dim3(nzb, 2), 256, 0, stream>>>((float4*)zbase, n4, targets, trT, trAr);
    k_match<<<dim3(PP / (256 * T1), BB), 256, 0, stream>>>(priors, trT, trAr, bto, bti, bpm);
    k_force<<<BB, 64, 0, stream>>>(bpm, bto, bti);
    k_loss<<<dim3(SS, BB), 256, 0, stream>>>(arm_loc, arm_conf, priors, targets,
                                             bto, bti, lcm, pll, pplc, pnp, Hc0, Hs0);
    k_scan<<<BB, 256, 0, stream>>>(Hc0, Hs0, NB0, 0, pnp, spre, srem, ssum, stb);
    k_hist<1><<<dim3(32, BB), 256, 0, stream>>>(lcm, spre, Hc1, Hs1);
    k_scan<<<BB, 256, 0, stream>>>(Hc1, Hs1, NB12, 1, pnp, spre, srem, ssum, stb);
    k_hist<2><<<dim3(32, BB), 256, 0, stream>>>(lcm, spre, Hc2, Hs2);
    k_scan<<<BB, 256, 0, stream>>>(Hc2, Hs2, NB12, 2, pnp, spre, srem, ssum, stb);
    k_final<<<1, 64, 0, stream>>>(pll, pplc, pnp, ssum, srem, stb, out);
}

// Round 3
// 267.087 us; speedup vs baseline: 1.0612x; 1.0325x over previous
//
#include <hip/hip_runtime.h>
#include <cstdint>

#pragma clang fp contract(off)

#define BB 64
#define PP 32768
#define OO 50
#define THRESH_F 0.5f
#define VAR0 0.1f
#define VAR1 0.2f
#define NEGPOS_I 3
#define SS 32            // k_ml grid.x = PP/(256*T1)
#define T1 4             // priors per thread in k_ml
#define NB0 2048         // pass-0 bins (bits 30:20)
#define NB12 1024        // pass-1/2 bins (10 bits each)

typedef unsigned long long u64;

// ---- K0: zero the atomically-accumulated region (Hc0/Hs0 + bpm) ----
__global__ void k_zero(float4* __restrict__ dst, int n4) {
    int i = blockIdx.x * blockDim.x + threadIdx.x;
    if (i < n4) dst[i] = make_float4(0.f, 0.f, 0.f, 0.f);
}

// wave64 max via DPP with identity old: row_shr 1/2/4/8 then row_bcast15
// (rows 1,3) and row_bcast31 (rows 2,3). Result in lane 63.
#define DPP_MAX(x, ctrl, rmask)                                              \
    {                                                                        \
        int _o = __float_as_int(x);                                          \
        x = fmaxf(x, __int_as_float(__builtin_amdgcn_update_dpp(             \
                _o, _o, (ctrl), (rmask), 0xf, false)));                      \
    }

// smooth-L1 of (arm_loc - encode(truth, prior)) — shared by k_ml and k_fix so
// the k_fix delta cancels bit-exactly when nothing changed.
__device__ __forceinline__ float sl1enc(const float* __restrict__ tb,
                                        float4 pr, float4 ld) {
    float gx = ((tb[0] + tb[2]) * 0.5f - pr.x) / (VAR0 * pr.z);
    float gy = ((tb[1] + tb[3]) * 0.5f - pr.y) / (VAR0 * pr.w);
    float gw = logf((tb[2] - tb[0]) / pr.z) / VAR1;
    float gh = logf((tb[3] - tb[1]) / pr.w) / VAR1;
    float g[4] = {gx, gy, gw, gh};
    float l[4] = {ld.x, ld.y, ld.z, ld.w};
    float s = 0.f;
    for (int q = 0; q < 4; ++q) {
        float d = l[q] - g[q];
        float ad = fabsf(d);
        s += (ad < 1.0f) ? 0.5f * d * d : ad - 0.5f;
    }
    return s;
}

// ---- K1: fused matcher + loss. Each thread owns T1 consecutive priors;
// t-loop computes each IoU once: row-best (regs) + column-best (DPP wave max
// -> one atomicMax per wave). Epilogue computes conf/lse/encode/smooth-L1,
// lcm, the pass-0 histogram, per-prior state byte (bpi), and block partials.
// Forced-match overrides are applied later by k_fix as exact deltas.
__global__ void __launch_bounds__(256, 8)
k_ml(const float* __restrict__ priors, const float* __restrict__ targets,
     const float* __restrict__ arm_loc, const float* __restrict__ arm_conf,
     float* __restrict__ lcm, unsigned char* __restrict__ bpi,
     u64* __restrict__ bpm,
     float* __restrict__ pll, float* __restrict__ pplc, int* __restrict__ pnp,
     int* __restrict__ Hc0, float* __restrict__ Hs0) {
    __shared__ float tr4[OO * 4];
    __shared__ float trA[OO];
    __shared__ int   trL[OO];
    __shared__ int   hc[NB0];
    __shared__ float hs[NB0];
    int b = blockIdx.y, tid = threadIdx.x;
    for (int i = tid; i < OO * 4; i += 256)
        tr4[i] = targets[(size_t)(b * OO + (i >> 2)) * 5 + (i & 3)];
    if (tid < OO)
        trL[tid] = (targets[(size_t)(b * OO + tid) * 5 + 4] >= 0.0f) ? 1 : 0;
    for (int i = tid; i < NB0; i += 256) { hc[i] = 0; hs[i] = 0.f; }
    __syncthreads();
    if (tid < OO)
        trA[tid] = (tr4[tid*4+2] - tr4[tid*4]) * (tr4[tid*4+3] - tr4[tid*4+1]);
    __syncthreads();

    int p0 = blockIdx.x * (256 * T1) + tid * T1;
    float bx0[T1], by0[T1], bx1[T1], by1[T1], aB[T1];
#pragma unroll
    for (int j = 0; j < T1; ++j) {
        float4 pr = ((const float4*)priors)[p0 + j];
        bx0[j] = pr.x - pr.z * 0.5f; by0[j] = pr.y - pr.w * 0.5f;
        bx1[j] = pr.x + pr.z * 0.5f; by1[j] = pr.y + pr.w * 0.5f;
        aB[j] = (bx1[j] - bx0[j]) * (by1[j] - by0[j]);
    }
    float rbv[T1]; int rbi[T1];
#pragma unroll
    for (int j = 0; j < T1; ++j) { rbv[j] = -1.0f; rbi[j] = 0; }

    for (int t = 0; t < OO; ++t) {
        float t0 = tr4[t*4], t1v = tr4[t*4+1], t2 = tr4[t*4+2], t3 = tr4[t*4+3];
        float aA = trA[t];
        float cbv = -1.0f; int cbp = 0;
#pragma unroll
        for (int j = 0; j < T1; ++j) {
            float ltx = fmaxf(t0, bx0[j]), lty = fmaxf(t1v, by0[j]);
            float rbx = fminf(t2, bx1[j]), rby = fminf(t3, by1[j]);
            float wx = fmaxf(rbx - ltx, 0.f), wy = fmaxf(rby - lty, 0.f);
            float inter = wx * wy;
            float v = inter / (aA + aB[j] - inter);
            if (v > rbv[j]) { rbv[j] = v; rbi[j] = t; }   // row: first-max
            if (v > cbv) { cbv = v; cbp = p0 + j; }       // col: smallest p on ties
        }
        float x = cbv;
        DPP_MAX(x, 0x111, 0xf);   // row_shr:1
        DPP_MAX(x, 0x112, 0xf);   // row_shr:2
        DPP_MAX(x, 0x114, 0xf);   // row_shr:4
        DPP_MAX(x, 0x118, 0xf);   // row_shr:8
        DPP_MAX(x, 0x142, 0xa);   // row_bcast:15 -> rows 1,3
        DPP_MAX(x, 0x143, 0xc);   // row_bcast:31 -> rows 2,3
        float mv = __int_as_float(__builtin_amdgcn_readlane(__float_as_int(x), 63));
        unsigned long long msk = __ballot(cbv == mv);
        int lane = (int)__ffsll((long long)msk) - 1;
        int pwin = __builtin_amdgcn_readlane(cbp, lane);
        if ((tid & 63) == 0) {
            u64 pk = ((u64)__float_as_uint(mv) << 32) | (unsigned)(PP - pwin);
            atomicMax(&bpm[b * OO + t], pk);
        }
    }

    // ---- epilogue: full loss for the un-forced matching ----
    size_t bp = (size_t)b * PP + p0;
    float4 ca = ((const float4*)arm_conf)[bp >> 1];
    float4 cb = ((const float4*)arm_conf)[(bp >> 1) + 1];
    float cs[8] = {ca.x, ca.y, ca.z, ca.w, cb.x, cb.y, cb.z, cb.w};

    float ll = 0.0f, plc = 0.0f; int np = 0;
    float outv[4]; unsigned pbyte = 0;
#pragma unroll
    for (int c = 0; c < 4; ++c) {
        int ti = rbi[c]; float ov = rbv[c];
        int conf = (ov < THRESH_F) ? 0 : trL[ti];
        float c0 = cs[c*2], c1 = cs[c*2+1];
        float m = fmaxf(c0, c1);
        float lse = logf(expf(c0 - m) + expf(c1 - m)) + m;
        bool pos = conf > 0;
        float lc = lse - (pos ? c1 : c0);
        outv[c] = pos ? 0.0f : lc;
        pbyte |= (unsigned)((pos ? 0x80u : 0u) | (unsigned)ti) << (8 * c);
        unsigned u = __float_as_uint(outv[c]);
        atomicAdd(&hc[u >> 20], 1);
        atomicAdd(&hs[u >> 20], outv[c]);
        if (pos) {
            np++; plc += lc;
            float4 pr = ((const float4*)priors)[p0 + c];
            float4 ld = ((const float4*)arm_loc)[bp + c];
            ll += sl1enc(&tr4[ti * 4], pr, ld);
        }
    }
    ((float4*)lcm)[bp >> 2] = make_float4(outv[0], outv[1], outv[2], outv[3]);
    ((unsigned*)bpi)[bp >> 2] = pbyte;

    __syncthreads();
    for (int i = tid; i < NB0; i += 256) {
        int cv = hc[i];
        if (cv) {
            atomicAdd(&Hc0[b * NB0 + i], cv);
            atomicAdd(&Hs0[b * NB0 + i], hs[i]);
        }
    }
    __syncthreads();
    // reuse hist LDS for the block reduce
    float* s1 = (float*)hc;          // [0..255]
    int*   s3 = hc + 256;            // [256..511]
    float* s2 = hs;                  // [0..255]
    s1[tid] = ll; s2[tid] = plc; s3[tid] = np;
    __syncthreads();
    for (int st = 128; st > 0; st >>= 1) {
        if (tid < st) { s1[tid] += s1[tid+st]; s2[tid] += s2[tid+st]; s3[tid] += s3[tid+st]; }
        __syncthreads();
    }
    if (tid == 0) {
        pll[blockIdx.x * BB + b] = s1[0];
        pplc[blockIdx.x * BB + b] = s2[0];
        pnp[blockIdx.x * BB + b] = s3[0];
    }
}

// ---- K2: forced-match fixup. One block (64 thr = 1 wave) per batch. Applies
// exact deltas for the <=50 forced priors (dedup: last truth wins), adjusts
// the pass-0 histogram + lcm, and publishes the batch num_pos (npb). ----
__global__ void k_fix(const u64* __restrict__ bpm, const float* __restrict__ targets,
                      const float* __restrict__ arm_loc, const float* __restrict__ arm_conf,
                      const float* __restrict__ priors, const unsigned char* __restrict__ bpi,
                      float* __restrict__ lcm,
                      float* __restrict__ pll, float* __restrict__ pplc,
                      int* __restrict__ pnp, int* __restrict__ npb,
                      int* __restrict__ Hc0, float* __restrict__ Hs0) {
    int b = blockIdx.x, j = threadIdx.x;
    int p = -1;
    if (j < OO) p = PP - (int)(unsigned)(bpm[b * OO + j] & 0xFFFFFFFFull);
    bool w = (j < OO);
    for (int jj = 1; jj < OO; ++jj) {
        int pj = __shfl(p, jj, 64);
        if (jj > j && pj == p) w = false;
    }
    float dll = 0.f, dplc = 0.f; int dnp = 0;
    if (w) {
        size_t bp = (size_t)b * PP + p;
        unsigned char ob = bpi[bp];
        bool old_pos = (ob & 0x80u) != 0;
        int old_ti = ob & 63;
        float2 cf = ((const float2*)arm_conf)[bp];
        float c0 = cf.x, c1 = cf.y;
        float m = fmaxf(c0, c1);
        float lse = logf(expf(c0 - m) + expf(c1 - m)) + m;
        const float* tbj = &targets[(size_t)(b * OO + j) * 5];
        bool new_pos = (tbj[4] >= 0.0f);
        float old_lcm = lcm[bp];
        float new_lcm = new_pos ? 0.0f : (lse - c0);
        unsigned uo = __float_as_uint(old_lcm), un = __float_as_uint(new_lcm);
        if (uo != un) {
            atomicAdd(&Hc0[b * NB0 + (uo >> 20)], -1);
            atomicAdd(&Hs0[b * NB0 + (uo >> 20)], -old_lcm);
            atomicAdd(&Hc0[b * NB0 + (un >> 20)], 1);
            atomicAdd(&Hs0[b * NB0 + (un >> 20)], new_lcm);
            lcm[bp] = new_lcm;
        }
        float4 pr = ((const float4*)priors)[p];
        float4 ld = ((const float4*)arm_loc)[bp];
        if (old_pos) {
            dnp -= 1; dplc -= (lse - c1);
            dll -= sl1enc(&targets[(size_t)(b * OO + old_ti) * 5], pr, ld);
        }
        if (new_pos) {
            dnp += 1; dplc += (lse - c1);
            dll += sl1enc(tbj, pr, ld);
        }
    }
    int myp = (j < SS) ? pnp[j * BB + b] : 0;
    for (int s = 32; s >= 1; s >>= 1) {
        dll += __shfl_down(dll, s, 64);
        dplc += __shfl_down(dplc, s, 64);
        dnp += __shfl_down(dnp, s, 64);
        myp += __shfl_down(myp, s, 64);
    }
    if (j == 0) {
        pll[b] += dll;           // slot s=0 of batch b
        pplc[b] += dplc;
        pnp[b] += dnp;
        npb[b] = myp + dnp;
    }
}

// ---- K3: fused 3-pass radix selection. One block per batch. Pass 0 scans the
// global 2048-bin hist; passes 1/2 re-histogram lcm in LDS and scan. Logic is
// verbatim from the previous k_scan/k_hist. ----
__global__ void __launch_bounds__(256)
k_sel(const float* __restrict__ lcm, const int* __restrict__ npb,
      int* __restrict__ Hc0, float* __restrict__ Hs0,
      float* __restrict__ ssum, int* __restrict__ srem, unsigned* __restrict__ stb) {
    __shared__ int hc[NB12]; __shared__ float hs[NB12];
    __shared__ int sc[256]; __shared__ float sf[256];
    __shared__ int s_chunk, s_r; __shared__ float s_S; __shared__ unsigned s_pref;
    int b = blockIdx.x, tid = threadIdx.x;

    // ---- pass 0 (2048 global bins, CH=8)
    {
        const int* hcg = Hc0 + b * NB0; const float* hsg = Hs0 + b * NB0;
        int c = 0; float f = 0.f; int base = tid * 8;
        for (int i = 0; i < 8; ++i) { c += hcg[base + i]; f += hsg[base + i]; }
        sc[tid] = c; sf[tid] = f;
        if (tid == 0) {
            int k = NEGPOS_I * npb[b]; if (k > PP - 1) k = PP - 1;
            s_r = k; s_S = 0.f;
        }
        __syncthreads();
        for (int off = 1; off < 256; off <<= 1) {
            int cv = (tid + off < 256) ? sc[tid + off] : 0;
            float fv = (tid + off < 256) ? sf[tid + off] : 0.f;
            __syncthreads(); sc[tid] += cv; sf[tid] += fv; __syncthreads();
        }
        int r = s_r;
        int nxt = (tid == 255) ? 0 : sc[tid + 1];
        if (sc[tid] >= r && nxt < r) s_chunk = tid;
        __syncthreads();
        if (tid == 0) {
            int ch = s_chunk;
            int r2 = r - ((ch == 255) ? 0 : sc[ch + 1]);
            float S2 = s_S + ((ch == 255) ? 0.f : sf[ch + 1]);
            int binSel = ch * 8;
            for (int i = 7; i >= 0; --i) {
                int bin = ch * 8 + i; int cbn = hcg[bin];
                if (r2 <= cbn) { binSel = bin; break; }
                r2 -= cbn; S2 += hsg[bin];
            }
            s_pref = (unsigned)binSel; s_r = r2; s_S = S2;
        }
        __syncthreads();
    }
    // ---- pass 1 (bits 19:10 of values with bits30:20 == pref)
    {
        for (int i = tid; i < NB12; i += 256) { hc[i] = 0; hs[i] = 0.f; }
        __syncthreads();
        unsigned pref = s_pref;
        const float4* v4 = (const float4*)(lcm + (size_t)b * PP);
        for (int it = 0; it < 32; ++it) {
            float4 x = v4[it * 256 + tid];
            float xs[4] = {x.x, x.y, x.z, x.w};
            for (int c2 = 0; c2 < 4; ++c2) {
                unsigned u = __float_as_uint(xs[c2]);
                if ((u >> 20) == pref) {
                    atomicAdd(&hc[(u >> 10) & 1023u], 1);
                    atomicAdd(&hs[(u >> 10) & 1023u], xs[c2]);
                }
            }
        }
        __syncthreads();
        int c = 0; float f = 0.f; int base = tid * 4;
        for (int i = 0; i < 4; ++i) { c += hc[base + i]; f += hs[base + i]; }
        sc[tid] = c; sf[tid] = f; __syncthreads();
        for (int off = 1; off < 256; off <<= 1) {
            int cv = (tid + off < 256) ? sc[tid + off] : 0;
            float fv = (tid + off < 256) ? sf[tid + off] : 0.f;
            __syncthreads(); sc[tid] += cv; sf[tid] += fv; __syncthreads();
        }
        int r = s_r;
        int nxt = (tid == 255) ? 0 : sc[tid + 1];
        if (sc[tid] >= r && nxt < r) s_chunk = tid;
        __syncthreads();
        if (tid == 0) {
            int ch = s_chunk;
            int r2 = r - ((ch == 255) ? 0 : sc[ch + 1]);
            float S2 = s_S + ((ch == 255) ? 0.f : sf[ch + 1]);
            int binSel = ch * 4;
            for (int i = 3; i >= 0; --i) {
                int bin = ch * 4 + i; int cbn = hc[bin];
                if (r2 <= cbn) { binSel = bin; break; }
                r2 -= cbn; S2 += hs[bin];
            }
            s_pref = (s_pref << 10) | (unsigned)binSel; s_r = r2; s_S = S2;
        }
        __syncthreads();
    }
    // ---- pass 2 (bits 9:0 of values with bits30:10 == pref)
    {
        for (int i = tid; i < NB12; i += 256) { hc[i] = 0; hs[i] = 0.f; }
        __syncthreads();
        unsigned pref = s_pref;
        const float4* v4 = (const float4*)(lcm + (size_t)b * PP);
        for (int it = 0; it < 32; ++it) {
            float4 x = v4[it * 256 + tid];
            float xs[4] = {x.x, x.y, x.z, x.w};
            for (int c2 = 0; c2 < 4; ++c2) {
                unsigned u = __float_as_uint(xs[c2]);
                if ((u >> 10) == pref) {
                    atomicAdd(&hc[u & 1023u], 1);
                    atomicAdd(&hs[u & 1023u], xs[c2]);
                }
            }
        }
        __syncthreads();
        int c = 0; float f = 0.f; int base = tid * 4;
        for (int i = 0; i < 4; ++i) { c += hc[base + i]; f += hs[base + i]; }
        sc[tid] = c; sf[tid] = f; __syncthreads();
        for (int off = 1; off < 256; off <<= 1) {
            int cv = (tid + off < 256) ? sc[tid + off] : 0;
            float fv = (tid + off < 256) ? sf[tid + off] : 0.f;
            __syncthreads(); sc[tid] += cv; sf[tid] += fv; __syncthreads();
        }
        int r = s_r;
        int nxt = (tid == 255) ? 0 : sc[tid + 1];
        if (sc[tid] >= r && nxt < r) s_chunk = tid;
        __syncthreads();
        if (tid == 0) {
            int ch = s_chunk;
            int r2 = r - ((ch == 255) ? 0 : sc[ch + 1]);
            float S2 = s_S + ((ch == 255) ? 0.f : sf[ch + 1]);
            int binSel = ch * 4;
            for (int i = 3; i >= 0; --i) {
                int bin = ch * 4 + i; int cbn = hc[bin];
                if (r2 <= cbn) { binSel = bin; break; }
                r2 -= cbn; S2 += hs[bin];
            }
            stb[b] = (s_pref << 10) | (unsigned)binSel;
            srem[b] = r2; ssum[b] = S2;
        }
    }
}

// ---- K4: final reduction across batches -> (loss_l/N, loss_c/N) ----
__global__ void k_final(const float* __restrict__ pll, const float* __restrict__ pplc,
                        const int* __restrict__ pnp, const float* __restrict__ ssum,
                        const int* __restrict__ srem, const unsigned* __restrict__ stb,
                        float* __restrict__ out) {
    int b = threadIdx.x;          // 64 threads = one wave, one batch each
    float ll = 0.f, plc = 0.f; int np = 0;
    for (int s = 0; s < SS; ++s) {
        ll += pll[s * BB + b];
        plc += pplc[s * BB + b];
        np += pnp[s * BB + b];
    }
    float tval = __uint_as_float(stb[b]);
    float cc = plc + ssum[b] + (float)srem[b] * tval;
    for (int s = 32; s > 0; s >>= 1) {
        ll += __shfl_down(ll, s);
        cc += __shfl_down(cc, s);
        np += __shfl_down(np, s);
    }
    if (b == 0) {
        float N = (float)np;
        out[0] = ll / N;
        out[1] = cc / N;
    }
}

extern "C" void kernel_launch(void* const* d_in, const int* in_sizes, int n_in,
                              void* d_out, int out_size, void* d_ws, size_t ws_size,
                              hipStream_t stream) {
    const float* arm_loc  = (const float*)d_in[0];
    const float* arm_conf = (const float*)d_in[1];
    const float* priors   = (const float*)d_in[4];
    const float* targets  = (const float*)d_in[5];
    float* out = (float*)d_out;

    char* w = (char*)d_ws;
    float* lcm = (float*)w;  w += sizeof(float) * (size_t)BB * PP;    // 8 MB
    unsigned char* bpi = (unsigned char*)w; w += (size_t)BB * PP;     // 2 MB
    // ---- zeroed region (atomically accumulated) ----
    char* zbase = w;
    int*   Hc0 = (int*)w;    w += sizeof(int)   * BB * NB0;
    float* Hs0 = (float*)w;  w += sizeof(float) * BB * NB0;
    u64*   bpm = (u64*)w;    w += sizeof(u64)   * BB * OO;
    size_t zbytes = (size_t)(w - zbase);
    // ---- plain written-before-read region ----
    float* pll  = (float*)w; w += sizeof(float) * BB * SS;
    float* pplc = (float*)w; w += sizeof(float) * BB * SS;
    int*   pnp  = (int*)w;   w += sizeof(int)   * BB * SS;
    int*   npb  = (int*)w;   w += sizeof(int)   * BB;
    unsigned* spre_unused = (unsigned*)w; w += sizeof(unsigned) * BB; (void)spre_unused;
    int*      srem = (int*)w;      w += sizeof(int) * BB;
    float*    ssum = (float*)w;    w += sizeof(float) * BB;
    unsigned* stb  = (unsigned*)w; w += sizeof(unsigned) * BB;

    int n4 = (int)(zbytes / 16);
    k_zero<<<(n4 + 255) / 256, 256, 0, stream>>>((float4*)zbase, n4);
    k_ml<<<dim3(SS, BB), 256, 0, stream>>>(priors, targets, arm_loc, arm_conf,
                                           lcm, bpi, bpm, pll, pplc, pnp, Hc0, Hs0);
    k_fix<<<BB, 64, 0, stream>>>(bpm, targets, arm_loc, arm_conf, priors, bpi,
                                 lcm, pll, pplc, pnp, npb, Hc0, Hs0);
    k_sel<<<BB, 256, 0, stream>>>(lcm, npb, Hc0, Hs0, ssum, srem, stb);
    k_final<<<1, 64, 0, stream>>>(pll, pplc, pnp, ssum, srem, stb, out);
}